// Round 7
// baseline (242.613 us; speedup 1.0000x reference)
//
#include <hip/hip_runtime.h>
#include <hip/hip_bf16.h>

typedef int  i32x4 __attribute__((ext_vector_type(4)));

// ---------------------------------------------------------------------------
// Prep 1: x fp32 -> int8 (per-row symmetric quant), rowsum folded to fp32.
// ---------------------------------------------------------------------------
__global__ __launch_bounds__(256) void prep_x_i8(const float* __restrict__ x,
                                                 int* __restrict__ xq,
                                                 float* __restrict__ rsum,
                                                 float* __restrict__ rscale,
                                                 int K) {
    const int row = blockIdx.x;
    const float* xr = x + (size_t)row * K;
    __shared__ float xs[4096];
    float mx = 0.f;
    for (int c = threadIdx.x * 4; c < K; c += blockDim.x * 4) {
        float4 v = *reinterpret_cast<const float4*>(xr + c);
        *reinterpret_cast<float4*>(xs + c) = v;
        mx = fmaxf(mx, fmaxf(fmaxf(fabsf(v.x), fabsf(v.y)),
                             fmaxf(fabsf(v.z), fabsf(v.w))));
    }
    #pragma unroll
    for (int off = 32; off > 0; off >>= 1) mx = fmaxf(mx, __shfl_down(mx, off));
    __shared__ float wmax[4];
    __shared__ float s_sx, s_inv;
    const int lane = threadIdx.x & 63, wv = threadIdx.x >> 6;
    if (lane == 0) wmax[wv] = mx;
    __syncthreads();
    if (threadIdx.x == 0) {
        float m = fmaxf(fmaxf(wmax[0], wmax[1]), fmaxf(wmax[2], wmax[3]));
        m = fmaxf(m, 1e-20f);
        s_sx = m / 127.f; s_inv = 127.f / m;
    }
    __syncthreads();
    const float inv = s_inv;
    int qs = 0;
    for (int c = threadIdx.x * 4; c < K; c += blockDim.x * 4) {
        float4 v = *reinterpret_cast<const float4*>(xs + c);
        const int q0 = __float2int_rn(v.x * inv), q1 = __float2int_rn(v.y * inv);
        const int q2 = __float2int_rn(v.z * inv), q3 = __float2int_rn(v.w * inv);
        qs += q0 + q1 + q2 + q3;
        const unsigned p = (unsigned)(q0 & 255) | ((unsigned)(q1 & 255) << 8) |
                           ((unsigned)(q2 & 255) << 16) | ((unsigned)(q3 & 255) << 24);
        xq[((size_t)row * K + c) >> 2] = (int)p;
    }
    #pragma unroll
    for (int off = 32; off > 0; off >>= 1) qs += __shfl_down(qs, off);
    __shared__ int wqs[4];
    if (lane == 0) wqs[wv] = qs;
    __syncthreads();
    if (threadIdx.x == 0) {
        const int t = wqs[0] + wqs[1] + wqs[2] + wqs[3];
        rsum[row] = s_sx * (float)t;
        rscale[row] = s_sx;
    }
}

// ---------------------------------------------------------------------------
// Prep 2: weight int32 codes -> int8 bytes. 16 codes / thread, 16B writes.
// ---------------------------------------------------------------------------
__global__ __launch_bounds__(256) void prep_w_i8(const int* __restrict__ w,
                                                 int* __restrict__ wq) {
    const size_t i = (size_t)blockIdx.x * blockDim.x + threadIdx.x;
    const int4* src = reinterpret_cast<const int4*>(w) + i * 4;
    int4 a = src[0], b = src[1], c = src[2], d = src[3];
    int4 o;
    o.x = (a.x & 255) | ((a.y & 255) << 8) | ((a.z & 255) << 16) | ((a.w & 255) << 24);
    o.y = (b.x & 255) | ((b.y & 255) << 8) | ((b.z & 255) << 16) | ((b.w & 255) << 24);
    o.z = (c.x & 255) | ((c.y & 255) << 8) | ((c.z & 255) << 16) | ((c.w & 255) << 24);
    o.w = (d.x & 255) | ((d.y & 255) << 8) | ((d.z & 255) << 16) | ((d.w & 255) << 24);
    reinterpret_cast<int4*>(wq)[i] = o;
}

// ---------------------------------------------------------------------------
// 128x128 int8 GEMM, ring-4 LDS (64 KiB -> 2 blocks/CU), counted lgkm/vmcnt.
// out[m,o] = sc[o]*(sx[m]*dot_i32[m,o] - zp[o]*rsum[m]) + bias[o]
// A: M x K i8 row-major; B: N x K i8 row-major (B^T GEMM).
// Slab = K=64 slice: 128 rows x 64 B = 8 KiB per operand; ring of 4 slabs.
// Swizzle: 16B slot within a row's 64B: phys = log ^ ((row>>1)&3); staged
// linearly via global_load_lds from inverse-swizzled global source.
// Phase s: READ frags(s+1) [8 ds_read_b128] | STAGE slab s+3 [4 gloads] |
// lgkmcnt(8) proves frags(s) | 16 MFMA | vmcnt(4) proves stage(s+2) | barrier.
// Stage(s+3) targets slot (s-1)&3 whose reads were lgkm-proven before the
// phase-(s-1) barrier -> hard write-safety. 2-phase landing slack for stages.
// PROLOGUE LEDGER (R6 fix): 12 gloads outstanding; vmcnt(4) proves BOTH
// STAGE(0) and STAGE(1) -- phase 0 reads slot 1 before any in-loop vmcnt,
// so STAGE(1) must be proven here (R5 used vmcnt(8): slab-1 landing race).
// ---------------------------------------------------------------------------
__device__ __forceinline__ void async16(void* lds, const void* g) {
    __builtin_amdgcn_global_load_lds(
        (const __attribute__((address_space(1))) unsigned*)g,
        (__attribute__((address_space(3))) unsigned*)lds, 16, 0, 0);
}

__global__ __launch_bounds__(256, 2) void qgemm4i(
    const char* __restrict__ A, const char* __restrict__ B,
    const float* __restrict__ rsum, const float* __restrict__ rscale,
    const float* __restrict__ scale, const float* __restrict__ zp,
    const float* __restrict__ bias, float* __restrict__ C,
    int M, int N, int K) {
    extern __shared__ char smem[];
    char* const AsR = smem;            // 4 x 8 KiB A slabs
    char* const BsR = smem + 32768;    // 4 x 8 KiB B slabs

    const int tid  = threadIdx.x;
    const int lane = tid & 63;
    const int wid  = tid >> 6;
    const int wm = wid >> 1, wn = wid & 1;   // 2 x 2 waves, wave tile 64x64
    const int l15 = lane & 15;

    // bijective XCD swizzle (gridDim.x % 8 == 0)
    const int nbn = N >> 7;                  // 32
    int wg = blockIdx.x;
    wg = (wg & 7) * (gridDim.x >> 3) + (wg >> 3);
    const int bm = wg / nbn, bn = wg % nbn;

    // per-thread staging source offsets (inverse-swizzled global address)
    const int r0s = tid >> 2, sls = tid & 3;
    size_t a_src[2], b_src[2];
    int lds_off[2];
    #pragma unroll
    for (int j = 0; j < 2; ++j) {
        const int row = r0s + j * 64;
        const int sl  = sls ^ ((row >> 1) & 3);
        a_src[j] = ((size_t)(bm * 128 + row)) * K + sl * 16;
        b_src[j] = ((size_t)(bn * 128 + row)) * K + sl * 16;
        lds_off[j] = (j * 256 + tid) * 16;
    }

    // stage slab u (K-slice u*64) into ring slot sl (A then B: 4 gloads)
    auto STAGE = [&](int u, int sl) {
        const int kc = u * 64;
        char* const da = AsR + sl * 8192;
        char* const db = BsR + sl * 8192;
        #pragma unroll
        for (int j = 0; j < 2; ++j) async16(da + lds_off[j], A + a_src[j] + kc);
        #pragma unroll
        for (int j = 0; j < 2; ++j) async16(db + lds_off[j], B + b_src[j] + kc);
    };

    // fragment-read constants (swizzled ds_read address)
    const int sw16 = (((lane >> 4) ^ ((lane >> 1) & 3)) << 4);
    const int a_ro = (wm * 64 + l15) * 64 + sw16;   // + m*1024
    const int b_ro = (wn * 64 + l15) * 64 + sw16;   // + n*1024

    i32x4 acc[4][4] = {};
    i32x4 afA[4], bfA[4], afB[4], bfB[4];

#define READF(AF, BF, SL)                                                      \
    {                                                                          \
        const char* _ha = AsR + (SL) * 8192;                                   \
        const char* _hb = BsR + (SL) * 8192;                                   \
        _Pragma("unroll")                                                      \
        for (int m = 0; m < 4; ++m)                                            \
            AF[m] = *(const i32x4*)(_ha + a_ro + m * 1024);                    \
        _Pragma("unroll")                                                      \
        for (int n = 0; n < 4; ++n)                                            \
            BF[n] = *(const i32x4*)(_hb + b_ro + n * 1024);                    \
    }

#define MFMA16(AF, BF)                                                         \
    __builtin_amdgcn_s_setprio(1);                                             \
    _Pragma("unroll")                                                          \
    for (int m = 0; m < 4; ++m)                                                \
        _Pragma("unroll")                                                      \
        for (int n = 0; n < 4; ++n)                                            \
            acc[m][n] = __builtin_amdgcn_mfma_i32_16x16x64_i8(                 \
                AF[m], BF[n], acc[m][n], 0, 0, 0);                             \
    __builtin_amdgcn_s_setprio(0);

#define LGKM8  asm volatile("s_waitcnt lgkmcnt(8)" ::: "memory");              \
               __builtin_amdgcn_sched_barrier(0);
#define VM4    asm volatile("s_waitcnt vmcnt(4)" ::: "memory");
#define ENDPH  __builtin_amdgcn_sched_barrier(0);                              \
               asm volatile("s_barrier" ::: "memory");

    const int NS = K >> 6;     // 64 slabs

    // ---- prologue: stage slabs 0,1,2; prove 0 AND 1; read frags(0) ----
    STAGE(0, 0); STAGE(1, 1); STAGE(2, 2);
    asm volatile("s_waitcnt vmcnt(4)" ::: "memory");
    asm volatile("s_barrier" ::: "memory");
    READF(afA, bfA, 0);

    #pragma unroll 1
    for (int i = 0; i < NS / 2; ++i) {
        const int s = 2 * i;
        {   // phase s: compute set A (slab s), read set B (slab s+1)
            READF(afB, bfB, (s + 1) & 3);
            int u = s + 3; if (u >= NS) u = NS - 1;
            STAGE(u, (s + 3) & 3);
            LGKM8
            MFMA16(afA, bfA);
            VM4
            ENDPH
        }
        {   // phase s+1: compute set B (slab s+1), read set A (slab s+2)
            READF(afA, bfA, (s + 2) & 3);
            int u = s + 4; if (u >= NS) u = NS - 1;
            STAGE(u, (s + 4) & 3);
            LGKM8
            MFMA16(afB, bfB);
            VM4
            ENDPH
        }
    }
#undef READF
#undef MFMA16
#undef LGKM8
#undef VM4
#undef ENDPH

    // ---- epilogue: dequant. D: col=lane&15, row=4*(lane>>4)+i ----
    float sc[4], zz[4], bb[4];
    #pragma unroll
    for (int n = 0; n < 4; ++n) {
        const int o = bn * 128 + wn * 64 + n * 16 + l15;
        sc[n] = scale[o]; zz[n] = zp[o]; bb[n] = bias[o];
    }
    const int hi4 = (lane >> 4) << 2;
    #pragma unroll
    for (int mf = 0; mf < 4; ++mf) {
        const int r0 = bm * 128 + wm * 64 + mf * 16 + hi4;
        float rs[4], sx[4];
        #pragma unroll
        for (int i = 0; i < 4; ++i) { rs[i] = rsum[r0 + i]; sx[i] = rscale[r0 + i]; }
        #pragma unroll
        for (int n = 0; n < 4; ++n) {
            const int o = bn * 128 + wn * 64 + n * 16 + l15;
            #pragma unroll
            for (int i = 0; i < 4; ++i)
                C[(size_t)(r0 + i) * N + o] =
                    sc[n] * (sx[i] * (float)acc[mf][n][i] - zz[n] * rs[i]) + bb[n];
        }
    }
}

// ---------------------------------------------------------------------------
extern "C" void kernel_launch(void* const* d_in, const int* in_sizes, int n_in,
                              void* d_out, int out_size, void* d_ws, size_t ws_size,
                              hipStream_t stream) {
    const float* x     = (const float*)d_in[0];
    const int*   w     = (const int*)d_in[1];
    const float* scale = (const float*)d_in[2];
    const float* zp    = (const float*)d_in[3];
    const float* bias  = (const float*)d_in[4];
    float* out = (float*)d_out;

    const int N = in_sizes[2];              // D_OUT = 4096
    const int K = in_sizes[1] / N;          // D_IN  = 4096
    const int M = in_sizes[0] / K;          // B*S   = 8192

    char*  xq  = (char*)d_ws;                                   // M*K bytes
    char*  wq  = (char*)d_ws + (size_t)M * K;                   // N*K bytes
    float* rs  = (float*)((char*)d_ws + (size_t)M * K + (size_t)N * K);
    float* rsc = rs + M;

    prep_x_i8<<<M, 256, 0, stream>>>(x, (int*)xq, rs, rsc, K);
    prep_w_i8<<<(int)(((size_t)N * K / 16) / 256), 256, 0, stream>>>(w, (int*)wq);

    (void)hipFuncSetAttribute((const void*)qgemm4i,
                              hipFuncAttributeMaxDynamicSharedMemorySize, 65536);
    const int nwg = (M / 128) * (N / 128);   // 2048, % 8 == 0
    qgemm4i<<<nwg, 256, 65536, stream>>>(xq, wq, rs, rsc, scale, zp, bias,
                                         out, M, N, K);
}